// Round 8
// baseline (1004.067 us; speedup 1.0000x reference)
//
#include <hip/hip_runtime.h>
#include <cstdint>
#include <cstddef>

// ---------------------------------------------------------------------------
// Residual VQ (SoundStream Alg.1) on MI355X — R11: prefetch depth + fused sweep.
// R10 post-mortem: spill elimination confirmed (WRITE 96.7->35.4 MB) but wall
// REGRESSED 448->612 -> R9's spills were latency-hidden; half-split overhead
// dominated. Reverted to R9. R9's residual stalls: (1) B-ring reload->consume
// distance only ~125 cyc (slot reloaded right after its MFMAs, consumed next
// sub-step) << L2/L3 latency; (2) epilogue does TWO 32-body cross-lane sweeps
// (pass1 ladders, pass3 ballots) + extra barrier + gmA round-trip.
// R11: (a) 3-slot register ring, q%3 slot rotation via reference-binding
// switch (static reg indexing), distance ~1 full iter (~330-375 cyc);
// (b) pass1+pass3 fused into ONE sweep collecting candidates vs WAVE-min
// (superset of global-min set since wave-min >= global-min -> provably safe;
// cap 4/wave unchanged). Pass2/4/5, margins, tiers verbatim R9.
// ---------------------------------------------------------------------------

#define BATCH 8
#define SEQ   2048
#define DIM   512
#define NUMQ  8
#define CODES 1024
#define NPTS  (BATCH*SEQ)            // 16384
#define MPTS  64                     // points per workgroup
#define NWG   (NPTS/MPTS)            // 256 = 1 WG per CU
#define NTHR  512                    // 8 waves
#define NCHUNK 32                    // K-steps of 16 per quantizer
#define NCHUNK_TOT (NUMQ*NCHUNK)     // 256 global chunks
#define CHUNK_BYTES 32768            // per global chunk: [w:8][g:2][c:128][j:8 f16]

#define OUT_IDX   (BATCH*SEQ*DIM)             // 8388608
#define OUT_LOSS  (OUT_IDX + BATCH*SEQ*NUMQ)  // 8519680

#define WS_LOSS   0                           // 8 doubles
#define WS_CNORM  1024                        // 8192 floats
#define WS_CBH    40960                       // f16 chunk images, 8.39 MB
#define WS_CNORMD (WS_CBH + NUMQ*NCHUNK*CHUNK_BYTES)  // 8192 doubles

typedef _Float16 f16x8  __attribute__((ext_vector_type(8)));
typedef _Float16 f16x4  __attribute__((ext_vector_type(4)));
typedef float    f32x16 __attribute__((ext_vector_type(16)));

__global__ void k_zero(double* loss) {
  if (threadIdx.x < NUMQ) loss[threadIdx.x] = 0.0;
}

// per-code squared norm (fp32; only feeds the approximate scores)
__global__ void k_cnorm(const float* __restrict__ cb, float* __restrict__ cnorm) {
  int r = blockIdx.x * blockDim.x + threadIdx.x;      // 0..8191
  const float* row = cb + (size_t)r * DIM;
  float s = 0.f;
  for (int d = 0; d < DIM; d += 4) {
    float4 v = *(const float4*)(row + d);
    s += v.x * v.x + v.y * v.y + v.z * v.z + v.w * v.w;
  }
  cnorm[r] = s;
}

// per-code squared norm, fp64 (feeds the exact refinement tiers)
__global__ void k_cnormd(const float* __restrict__ cb, double* __restrict__ cnd) {
  int r = blockIdx.x * blockDim.x + threadIdx.x;      // 0..8191
  const float4* row = (const float4*)(cb + (size_t)r * DIM);
  double d0 = 0, d1 = 0, d2 = 0, d3 = 0;
  for (int i = 0; i < 128; i += 4) {
    float4 a = row[i], b = row[i + 1], c = row[i + 2], d = row[i + 3];
    d0 += (double)a.x * a.x + (double)a.y * a.y + (double)a.z * a.z + (double)a.w * a.w;
    d1 += (double)b.x * b.x + (double)b.y * b.y + (double)b.z * b.z + (double)b.w * b.w;
    d2 += (double)c.x * c.x + (double)c.y * c.y + (double)c.z * c.z + (double)c.w * c.w;
    d3 += (double)d.x * d.x + (double)d.y * d.y + (double)d.z * d.z + (double)d.w * d.w;
  }
  cnd[r] = (d0 + d1) + (d2 + d3);
}

// Build f16 codebook chunk images, PER-WAVE sub-chunks (verbatim R6-R9):
//   chunk n=(q,ks): 8 sub-chunks of 4 KB, one per wave w (codes w*128..+127)
//   sub-chunk layout [g:2][c:128][j:8 f16]; element = cb[q][w*128+c][ks*16+g*8+j]
__global__ void k_prep(const float* __restrict__ cb, unsigned char* __restrict__ cbH) {
  unsigned u = blockIdx.x * blockDim.x + threadIdx.x;   // 0..1048575 (8B units)
  unsigned h  = u & 1;                 // j-half (4 f16)
  unsigned v  = u >> 1;                // 16B granule
  unsigned c  = v & 127;
  unsigned g  = (v >> 7) & 1;
  unsigned w  = (v >> 8) & 7;
  unsigned ks = (v >> 11) & 31;
  unsigned q  = v >> 16;
  unsigned code = (w << 7) | c;
  unsigned k = ks * 16 + g * 8 + h * 4;
  float4 val = *(const float4*)(cb + ((size_t)((q << 10) | code)) * DIM + k);
  f16x4 o;
  o[0] = (_Float16)val.x; o[1] = (_Float16)val.y;
  o[2] = (_Float16)val.z; o[3] = (_Float16)val.w;
  *(f16x4*)(cbH + (size_t)u * 8) = o;
}

// one chunk's 4 B-fragments for this lane (4x global_load_dwordx4, coalesced)
struct BF { f16x8 b0, b1, b2, b3; };
__device__ __forceinline__ BF loadB(const unsigned char* __restrict__ p) {
  BF r;
  r.b0 = *(const f16x8*)(p);
  r.b1 = *(const f16x8*)(p + 512);
  r.b2 = *(const f16x8*)(p + 1024);
  r.b3 = *(const f16x8*)(p + 1536);
  return r;
}

__launch_bounds__(NTHR, 2)
__global__ void k_main(const float* __restrict__ x, const float* __restrict__ cb,
                       const unsigned char* __restrict__ cbH,
                       const float* __restrict__ cnorm,
                       const double* __restrict__ cnormd,
                       double* __restrict__ lossAcc,
                       float* __restrict__ out)
{
  // A-plane: f16 resid, row m (64) x 512 k; 16B slot s=k/8 stored at
  // slot' = swap3(s) ^ (m&31) -> minimal-conflict b128 reads and writes.
  __shared__ __align__(16) unsigned char Af[MPTS * DIM * 2];    // 64 KB
  __shared__ float          s1w[MPTS][8];
  __shared__ unsigned short id1w[MPTS][8];
  __shared__ unsigned short cand[MPTS][8][4];
  __shared__ unsigned char  ccnt[MPTS][8];
  __shared__ int            win0A[MPTS];
  __shared__ unsigned short idxs[MPTS][NUMQ];
  __shared__ double         lred[8];

  const int tid = threadIdx.x;
  const int cl  = tid & 63;
  const int w   = tid >> 6;          // wave 0..7; owns codes w*128..+127
  const int l31 = cl & 31;
  const int l5  = cl >> 5;           // k-group within wave
  const int wg  = blockIdx.x;

  // residual registers: thread owns point rp = tid>>3, dims rj*64 .. +64
  const int rp = tid >> 3;
  const int rj = tid & 7;
  const size_t gp = (size_t)wg * MPTS + rp;
  float4 r4[16];
  {
    const float4* xr = (const float4*)(x + gp * DIM + rj * 64);
    #pragma unroll
    for (int i = 0; i < 16; ++i) r4[i] = xr[i];
  }

  // per-lane base into the chunk image; chunk gid at base + gid*32KB
  const unsigned char* base = cbH + (w << 12) + (l5 << 11) + (l31 << 4);

  // 3-slot B register ring; invariant at q start (rotated by q%3):
  //   rot(q)[0]=chunk q*32+0, rot(q)[1]=+1, rot(q)[2]=+2
  BF s0 = loadB(base);
  BF s1 = loadB(base + (size_t)1 * CHUNK_BYTES);
  BF s2 = loadB(base + (size_t)2 * CHUNK_BYTES);

  for (int q = 0; q < NUMQ; ++q) {
    // ---- A-plane build: f16(resid), swizzled (verbatim R9)
    #pragma unroll
    for (int i = 0; i < 8; ++i) {
      float4 a = r4[2 * i], b = r4[2 * i + 1];
      f16x8 v;
      v[0] = (_Float16)a.x; v[1] = (_Float16)a.y; v[2] = (_Float16)a.z; v[3] = (_Float16)a.w;
      v[4] = (_Float16)b.x; v[5] = (_Float16)b.y; v[6] = (_Float16)b.z; v[7] = (_Float16)b.w;
      int sl = ((i << 3) | rj) ^ (rp & 31);            // swap3(j*8+i) ^ row
      *(f16x8*)(Af + rp * 1024 + (sl << 4)) = v;
    }
    __syncthreads();

    f32x16 acc[2][4];
    #pragma unroll
    for (int mt = 0; mt < 2; ++mt)
      #pragma unroll
      for (int nt = 0; nt < 4; ++nt)
        #pragma unroll
        for (int e = 0; e < 16; ++e) acc[mt][nt][e] = 0.0f;

    // one K sub-step: MFMA chunk ks from slot S
    auto sub = [&](int ks, BF& S) {
      const int s5 = (ks << 1) | l5;
      const int sf = ((((s5 & 7) << 3) | (s5 >> 3)) ^ l31) << 4;
      f16x8 a0 = *(const f16x8*)(Af + l31 * 1024 + sf);
      f16x8 a1 = *(const f16x8*)(Af + 32768 + l31 * 1024 + sf);
      __builtin_amdgcn_s_setprio(1);
      acc[0][0] = __builtin_amdgcn_mfma_f32_32x32x16_f16(a0, S.b0, acc[0][0], 0, 0, 0);
      acc[0][1] = __builtin_amdgcn_mfma_f32_32x32x16_f16(a0, S.b1, acc[0][1], 0, 0, 0);
      acc[0][2] = __builtin_amdgcn_mfma_f32_32x32x16_f16(a0, S.b2, acc[0][2], 0, 0, 0);
      acc[0][3] = __builtin_amdgcn_mfma_f32_32x32x16_f16(a0, S.b3, acc[0][3], 0, 0, 0);
      acc[1][0] = __builtin_amdgcn_mfma_f32_32x32x16_f16(a1, S.b0, acc[1][0], 0, 0, 0);
      acc[1][1] = __builtin_amdgcn_mfma_f32_32x32x16_f16(a1, S.b1, acc[1][1], 0, 0, 0);
      acc[1][2] = __builtin_amdgcn_mfma_f32_32x32x16_f16(a1, S.b2, acc[1][2], 0, 0, 0);
      acc[1][3] = __builtin_amdgcn_mfma_f32_32x32x16_f16(a1, S.b3, acc[1][3], 0, 0, 0);
      __builtin_amdgcn_s_setprio(0);
    };

    // K-phase with slot roles (A,B,C) = rotation(q%3); reload distance ~1 iter
    auto kphase = [&](BF& A, BF& B, BF& C) {
      const int g0 = q << 5;
      #pragma unroll 1
      for (int kk = 0; kk < 30; kk += 3) {
        sub(kk, A);
        A = loadB(base + (size_t)(g0 + kk + 3) * CHUNK_BYTES);      // gid<=254
        sub(kk + 1, B);
        B = loadB(base + (size_t)(g0 + kk + 4) * CHUNK_BYTES);      // gid<=255
        sub(kk + 2, C);
        { const int gid = g0 + kk + 5;                               // gid<=256!
          if (gid < NCHUNK_TOT) C = loadB(base + (size_t)gid * CHUNK_BYTES); }
      }
      sub(30, A);
      { const int gid = g0 + 33;
        if (gid < NCHUNK_TOT) A = loadB(base + (size_t)gid * CHUNK_BYTES); }
      sub(31, B);
      { const int gid = g0 + 34;
        if (gid < NCHUNK_TOT) B = loadB(base + (size_t)gid * CHUNK_BYTES); }
      // end state: C=c0', A=c1', B=c2'  -> rotation(q+1)
    };
    switch (q % 3) {
      case 0: kphase(s0, s1, s2); break;
      case 1: kphase(s2, s0, s1); break;
      default: kphase(s1, s2, s0); break;
    }

    // ---- scores = -2*dot + ||c||^2 (approximate; f16-rounded inputs)
    {
      const float* cnq = cnorm + (q << 10) + (w << 7) + l31;
      const float cn0 = cnq[0], cn1 = cnq[32], cn2 = cnq[64], cn3 = cnq[96];
      #pragma unroll
      for (int mt = 0; mt < 2; ++mt) {
        acc[mt][0] = acc[mt][0] * -2.0f + cn0;
        acc[mt][1] = acc[mt][1] * -2.0f + cn1;
        acc[mt][2] = acc[mt][2] * -2.0f + cn2;
        acc[mt][3] = acc[mt][3] * -2.0f + cn3;
      }
    }

    // ---- FUSED pass 1+3: single sweep per (mt,r): wave-min ladder + id
    //      recovery + candidate ballots vs WAVE-min margin (superset of the
    //      global-min set since wave-min >= global-min; cap 4/wave as proven).
    // C/D layout 32x32: col = lane&31, row = (r&3)+8*(r>>2)+4*(lane>>5)
    #pragma unroll
    for (int mt = 0; mt < 2; ++mt)
      #pragma unroll
      for (int r = 0; r < 16; ++r) {
        float s = acc[mt][0][r]; int bi = l31;
        if (acc[mt][1][r] < s) { s = acc[mt][1][r]; bi = 32 + l31; }
        if (acc[mt][2][r] < s) { s = acc[mt][2][r]; bi = 64 + l31; }
        if (acc[mt][3][r] < s) { s = acc[mt][3][r]; bi = 96 + l31; }
        float smin = s;
        #pragma unroll
        for (int m = 1; m < 32; m <<= 1) smin = fminf(smin, __shfl_xor(smin, m));
        unsigned long long bm = __ballot(s == smin);
        unsigned halfm = l5 ? (unsigned)(bm >> 32) : (unsigned)bm;
        int first = __builtin_ctz(halfm) + (l5 << 5);
        int id = __shfl(bi, first);
        const float lim = smin + 1.5f + 1e-4f * fabsf(smin);
        unsigned long long b0 = __ballot(acc[mt][0][r] <= lim);
        unsigned long long b1 = __ballot(acc[mt][1][r] <= lim);
        unsigned long long b2 = __ballot(acc[mt][2][r] <= lim);
        unsigned long long b3 = __ballot(acc[mt][3][r] <= lim);
        if (l31 == 0) {
          const int p = mt * 32 + (r & 3) + 8 * (r >> 2) + 4 * l5;
          s1w[p][w] = smin; id1w[p][w] = (unsigned short)id;
          unsigned short* cd = &cand[p][w][0];
          unsigned m0 = (cl == 0) ? (unsigned)b0 : (unsigned)(b0 >> 32);
          unsigned m1 = (cl == 0) ? (unsigned)b1 : (unsigned)(b1 >> 32);
          unsigned m2 = (cl == 0) ? (unsigned)b2 : (unsigned)(b2 >> 32);
          unsigned m3 = (cl == 0) ? (unsigned)b3 : (unsigned)(b3 >> 32);
          int n = 0;
          while (m0 && n < 4) { int bt = __builtin_ctz(m0); m0 &= m0 - 1; cd[n++] = (unsigned short)(bt); }
          while (m1 && n < 4) { int bt = __builtin_ctz(m1); m1 &= m1 - 1; cd[n++] = (unsigned short)(32 + bt); }
          while (m2 && n < 4) { int bt = __builtin_ctz(m2); m2 &= m2 - 1; cd[n++] = (unsigned short)(64 + bt); }
          while (m3 && n < 4) { int bt = __builtin_ctz(m3); m3 &= m3 - 1; cd[n++] = (unsigned short)(96 + bt); }
          ccnt[p][w] = (unsigned char)n;
        }
      }
    __syncthreads();

    // ---- pass 2: global min + provisional winner per point
    if (tid < MPTS) {
      int p = tid;
      float bs = s1w[p][0]; int bi = id1w[p][0];
      #pragma unroll
      for (int ww = 1; ww < 8; ++ww) {
        float s = s1w[p][ww];
        if (s < bs) { bs = s; bi = ww * 128 + id1w[p][ww]; }
      }
      win0A[p] = bi;
    }
    __syncthreads();

    // ---- pass 4: refinement tiers, 8-lane-group parallel (verbatim R9)
    {
      const int g  = cl >> 3;
      const int gl = cl & 7;
      const int p  = (w << 3) + g;          // == rp
      int tot = 0;
      #pragma unroll
      for (int ww = 0; ww < 8; ++ww) tot += ccnt[p][ww];
      int winner = win0A[p];
      int mtot = tot;
      #pragma unroll
      for (int m = 1; m < 64; m <<= 1) { int o = __shfl_xor(mtot, m); if (o > mtot) mtot = o; }
      if (mtot > 1) {
        double bs = 1.0e300, bs2 = 1.0e300; int bi = 0x7FFFFFFF;
        #pragma unroll 1
        for (int k = 0; k < mtot; ++k) {
          int cc = -1;
          if (tot > 1 && k < tot) {
            int rem = k, ww = 0;
            #pragma unroll 1
            for (; ww < 7; ++ww) { int nn = ccnt[p][ww]; if (rem < nn) break; rem -= nn; }
            cc = ww * 128 + cand[p][ww][rem];
          }
          double dt = 0.0;
          if (cc >= 0) {
            // tier 1: fp64 dot vs exact fp32 residual (in regs), 4-way ILP
            const float4* cr = (const float4*)(cb + ((size_t)q * CODES + cc) * DIM + gl * 64);
            double d0 = 0, d1 = 0, d2 = 0, d3 = 0;
            #pragma unroll
            for (int i = 0; i < 16; i += 4) {
              float4 c0 = cr[i], c1 = cr[i + 1], c2 = cr[i + 2], c3 = cr[i + 3];
              d0 += (double)r4[i].x * c0.x + (double)r4[i].y * c0.y
                  + (double)r4[i].z * c0.z + (double)r4[i].w * c0.w;
              d1 += (double)r4[i + 1].x * c1.x + (double)r4[i + 1].y * c1.y
                  + (double)r4[i + 1].z * c1.z + (double)r4[i + 1].w * c1.w;
              d2 += (double)r4[i + 2].x * c2.x + (double)r4[i + 2].y * c2.y
                  + (double)r4[i + 2].z * c2.z + (double)r4[i + 2].w * c2.w;
              d3 += (double)r4[i + 3].x * c3.x + (double)r4[i + 3].y * c3.y
                  + (double)r4[i + 3].z * c3.z + (double)r4[i + 3].w * c3.w;
            }
            dt = (d0 + d1) + (d2 + d3);
          }
          #pragma unroll
          for (int m = 1; m < 8; m <<= 1) dt += __shfl_xor(dt, m);
          if (cc >= 0) {
            double s = -2.0 * dt + cnormd[(q << 10) + cc];
            if (s < bs) { bs2 = bs; bs = s; bi = cc; }
            else if (s < bs2) { bs2 = s; }
          }
        }
        // tier 2: exact fp64 chain rebuild from x (rare: <1e-3 gap)
        if (tot > 1 && bs2 - bs <= 1e-3 + 1e-6 * fabs(bs)) {
          bs = 1.0e300; bi = 0x7FFFFFFF;
          const float4* xr2 = (const float4*)(x + gp * DIM + gl * 64);
          #pragma unroll 1
          for (int k = 0; k < tot; ++k) {
            int rem = k, ww = 0;
            #pragma unroll 1
            for (; ww < 7; ++ww) { int nn = ccnt[p][ww]; if (rem < nn) break; rem -= nn; }
            const int cc = ww * 128 + cand[p][ww][rem];
            const float4* cr = (const float4*)(cb + ((size_t)q * CODES + cc) * DIM + gl * 64);
            double dt = 0.0;
            #pragma unroll 1
            for (int i = 0; i < 16; ++i) {
              float4 xv = xr2[i];
              double rhx = xv.x, rhy = xv.y, rhz = xv.z, rhw = xv.w;
              #pragma unroll 1
              for (int t2 = 0; t2 < q; ++t2) {
                const float4* qr = (const float4*)(cb + ((size_t)t2 * CODES + idxs[p][t2]) * DIM + gl * 64);
                float4 qv = qr[i];
                rhx -= (double)qv.x; rhy -= (double)qv.y;
                rhz -= (double)qv.z; rhw -= (double)qv.w;
              }
              float4 cv = cr[i];
              dt += rhx * cv.x + rhy * cv.y + rhz * cv.z + rhw * cv.w;
            }
            #pragma unroll
            for (int m = 1; m < 8; m <<= 1) dt += __shfl_xor(dt, m);
            double s = -2.0 * dt + cnormd[(q << 10) + cc];
            if (s < bs || (s == bs && cc < bi)) { bs = s; bi = cc; }
          }
        }
        if (tot > 1) winner = bi;
      }
      if (gl == 0) idxs[p][q] = (unsigned short)winner;
    }
    __syncthreads();

    // ---- pass 5: residual update (exact fp32 chain) + commit loss (fp64,
    //      2-way ILP partials) — verbatim R9
    {
      const int win = idxs[rp][q];
      const float4* cr = (const float4*)(cb + ((size_t)q * CODES + win) * DIM + rj * 64);
      double ls0 = 0.0, ls1 = 0.0;
      #pragma unroll
      for (int i = 0; i < 16; i += 2) {
        float4 c0 = cr[i], c1 = cr[i + 1];
        float dx0 = c0.x - r4[i].x, dy0 = c0.y - r4[i].y;
        float dz0 = c0.z - r4[i].z, dw0 = c0.w - r4[i].w;
        ls0 += (double)dx0 * dx0 + (double)dy0 * dy0 + (double)dz0 * dz0 + (double)dw0 * dw0;
        r4[i].x -= c0.x; r4[i].y -= c0.y; r4[i].z -= c0.z; r4[i].w -= c0.w;
        float dx1 = c1.x - r4[i + 1].x, dy1 = c1.y - r4[i + 1].y;
        float dz1 = c1.z - r4[i + 1].z, dw1 = c1.w - r4[i + 1].w;
        ls1 += (double)dx1 * dx1 + (double)dy1 * dy1 + (double)dz1 * dz1 + (double)dw1 * dw1;
        r4[i + 1].x -= c1.x; r4[i + 1].y -= c1.y; r4[i + 1].z -= c1.z; r4[i + 1].w -= c1.w;
      }
      double ls = ls0 + ls1;
      #pragma unroll
      for (int m = 1; m < 64; m <<= 1) ls += __shfl_xor(ls, m);
      if (cl == 0) lred[w] = ls;
      __syncthreads();
      if (tid == 0) {
        double t = lred[0] + lred[1] + lred[2] + lred[3]
                 + lred[4] + lred[5] + lred[6] + lred[7];
        atomicAdd(lossAcc + q, t);
      }
      __syncthreads();
    }
  } // q

  // ---- outputs: quantized = x - resid_final; indices as float
  {
    const float4* xr = (const float4*)(x + gp * DIM + rj * 64);
    float4* orow = (float4*)(out + gp * DIM + rj * 64);
    #pragma unroll
    for (int i = 0; i < 16; ++i) {
      float4 xv = xr[i];
      float4 o;
      o.x = xv.x - r4[i].x; o.y = xv.y - r4[i].y;
      o.z = xv.z - r4[i].z; o.w = xv.w - r4[i].w;
      orow[i] = o;
    }
  }
  if (tid < MPTS) {
    float* ob = out + OUT_IDX + ((size_t)wg * MPTS + tid) * NUMQ;
    #pragma unroll
    for (int j = 0; j < NUMQ; ++j) ob[j] = (float)idxs[tid][j];
  }
}

__global__ void k_fin(const double* __restrict__ loss, float* __restrict__ out) {
  int t = threadIdx.x;
  if (t < NUMQ)
    out[OUT_LOSS + t] = (float)(loss[t] / (double)((size_t)BATCH * SEQ * DIM));
}

extern "C" void kernel_launch(void* const* d_in, const int* in_sizes, int n_in,
                              void* d_out, int out_size, void* d_ws, size_t ws_size,
                              hipStream_t stream) {
  (void)in_sizes; (void)n_in; (void)out_size; (void)ws_size;
  const float* x  = (const float*)d_in[0];
  const float* cb = (const float*)d_in[1];
  float* out = (float*)d_out;
  char* ws = (char*)d_ws;
  double* loss = (double*)(ws + WS_LOSS);
  float* cnorm = (float*)(ws + WS_CNORM);
  unsigned char* cbH = (unsigned char*)(ws + WS_CBH);   // 8.39 MB
  double* cnormd = (double*)(ws + WS_CNORMD);           // 64 KB

  k_zero<<<1, 64, 0, stream>>>(loss);
  k_cnorm<<<NUMQ * CODES / 256, 256, 0, stream>>>(cb, cnorm);
  k_cnormd<<<NUMQ * CODES / 256, 256, 0, stream>>>(cb, cnormd);
  k_prep<<<NUMQ * NCHUNK * CHUNK_BYTES / 8 / 256, 256, 0, stream>>>(cb, cbH);
  k_main<<<NWG, NTHR, 0, stream>>>(x, cb, cbH, cnorm, cnormd, loss, out);
  k_fin<<<1, 64, 0, stream>>>(loss, out);
}

// Round 9
// 1002.797 us; speedup vs baseline: 1.0013x; 1.0013x over previous
//
#include <hip/hip_runtime.h>
#include <cstdint>
#include <cstddef>

// ---------------------------------------------------------------------------
// Residual VQ (SoundStream Alg.1) on MI355X — R12: launch fusion + lean epilogue.
// R11 post-mortem: 3-slot ring + lambda kphase -> wholesale acc spills
// (WRITE 309 MB), 448->941. K-loop frozen at R9's proven form (2-slot ring).
// R12, three surgical edits:
//  1) prep kernels fused 4->1 (k_zero+k_cnorm+k_cnormd+k_prep); 5 launches->2
//     (bench paid ~95 us outside k_main).
//  2) k_fin folded into k_main: device-scope done-counter, last-finishing
//     block writes loss outputs (dispatch-order-free, G16-safe; lossAcc read
//     via atomicAdd(p,0.0) for cross-XCD coherence).
//  3) epilogue: fused pass1+3 single sweep (R11's proven-correct half) with
//     wave-min margin (superset of global-min set -> safe); pass 2 absorbed
//     into pass 4 prologue as 8-lane-group shfl argmin (tie: lowest wave,
//     same as R9). Removes one 32-body sweep, one phase, two barriers.
// K-loop, A-plane, margin 1.5, tier-1/tier-2 exactness verbatim R9.
// ---------------------------------------------------------------------------

#define BATCH 8
#define SEQ   2048
#define DIM   512
#define NUMQ  8
#define CODES 1024
#define NPTS  (BATCH*SEQ)            // 16384
#define MPTS  64                     // points per workgroup
#define NWG   (NPTS/MPTS)            // 256 = 1 WG per CU
#define NTHR  512                    // 8 waves
#define NCHUNK 32                    // K-steps of 16 per quantizer
#define CHUNK_BYTES 32768            // per global chunk: [w:8][g:2][c:128][j:8 f16]

#define OUT_IDX   (BATCH*SEQ*DIM)             // 8388608
#define OUT_LOSS  (OUT_IDX + BATCH*SEQ*NUMQ)  // 8519680

#define WS_LOSS   0                           // 8 doubles
#define WS_CNORM  1024                        // 8192 floats
#define WS_CBH    40960                       // f16 chunk images, 8.39 MB
#define WS_CNORMD (WS_CBH + NUMQ*NCHUNK*CHUNK_BYTES)  // 8192 doubles
#define WS_DONE   (WS_CNORMD + 8192*8)        // 1 unsigned

typedef _Float16 f16x8  __attribute__((ext_vector_type(8)));
typedef _Float16 f16x4  __attribute__((ext_vector_type(4)));
typedef float    f32x16 __attribute__((ext_vector_type(16)));

// ---- fused prep: chunk-image build + fp32/fp64 code norms + zeroing -------
// grid 4096 x 256. u = global thread = 8B unit of the image (verbatim R9 map).
__global__ void k_prep(const float* __restrict__ cb, unsigned char* __restrict__ cbH,
                       float* __restrict__ cnorm, double* __restrict__ cnd,
                       double* __restrict__ loss, unsigned* __restrict__ done) {
  unsigned u = blockIdx.x * blockDim.x + threadIdx.x;   // 0..1048575
  {
    unsigned h  = u & 1;                 // j-half (4 f16)
    unsigned v  = u >> 1;                // 16B granule
    unsigned c  = v & 127;
    unsigned g  = (v >> 7) & 1;
    unsigned w  = (v >> 8) & 7;
    unsigned ks = (v >> 11) & 31;
    unsigned q  = v >> 16;
    unsigned code = (w << 7) | c;
    unsigned k = ks * 16 + g * 8 + h * 4;
    float4 val = *(const float4*)(cb + ((size_t)((q << 10) | code)) * DIM + k);
    f16x4 o;
    o[0] = (_Float16)val.x; o[1] = (_Float16)val.y;
    o[2] = (_Float16)val.z; o[3] = (_Float16)val.w;
    *(f16x4*)(cbH + (size_t)u * 8) = o;
  }
  if (u < NUMQ) loss[u] = 0.0;
  if (u == NUMQ) *done = 0u;
  if (u < NUMQ * CODES) {              // one thread per code row: both norms
    const float4* row = (const float4*)(cb + (size_t)u * DIM);
    float s = 0.f;
    double d0 = 0, d1 = 0, d2 = 0, d3 = 0;
    for (int i = 0; i < 128; i += 4) {
      float4 a = row[i], b = row[i + 1], c2 = row[i + 2], d = row[i + 3];
      s += a.x * a.x + a.y * a.y + a.z * a.z + a.w * a.w
         + b.x * b.x + b.y * b.y + b.z * b.z + b.w * b.w
         + c2.x * c2.x + c2.y * c2.y + c2.z * c2.z + c2.w * c2.w
         + d.x * d.x + d.y * d.y + d.z * d.z + d.w * d.w;
      d0 += (double)a.x * a.x + (double)a.y * a.y + (double)a.z * a.z + (double)a.w * a.w;
      d1 += (double)b.x * b.x + (double)b.y * b.y + (double)b.z * b.z + (double)b.w * b.w;
      d2 += (double)c2.x * c2.x + (double)c2.y * c2.y + (double)c2.z * c2.z + (double)c2.w * c2.w;
      d3 += (double)d.x * d.x + (double)d.y * d.y + (double)d.z * d.z + (double)d.w * d.w;
    }
    cnorm[u] = s;
    cnd[u] = (d0 + d1) + (d2 + d3);
  }
}

// one chunk's 4 B-fragments for this lane (4x global_load_dwordx4, coalesced)
struct BF { f16x8 b0, b1, b2, b3; };
__device__ __forceinline__ BF loadB(const unsigned char* __restrict__ p) {
  BF r;
  r.b0 = *(const f16x8*)(p);
  r.b1 = *(const f16x8*)(p + 512);
  r.b2 = *(const f16x8*)(p + 1024);
  r.b3 = *(const f16x8*)(p + 1536);
  return r;
}

__launch_bounds__(NTHR, 2)
__global__ void k_main(const float* __restrict__ x, const float* __restrict__ cb,
                       const unsigned char* __restrict__ cbH,
                       const float* __restrict__ cnorm,
                       const double* __restrict__ cnormd,
                       double* __restrict__ lossAcc,
                       unsigned* __restrict__ done,
                       float* __restrict__ out)
{
  // A-plane: f16 resid, row m (64) x 512 k; 16B slot s=k/8 stored at
  // slot' = swap3(s) ^ (m&31) -> minimal-conflict b128 reads and writes.
  __shared__ __align__(16) unsigned char Af[MPTS * DIM * 2];    // 64 KB
  __shared__ float          s1w[MPTS][8];
  __shared__ unsigned short id1w[MPTS][8];
  __shared__ unsigned short cand[MPTS][8][4];
  __shared__ unsigned char  ccnt[MPTS][8];
  __shared__ unsigned short idxs[MPTS][NUMQ];
  __shared__ double         lred[8];

  const int tid = threadIdx.x;
  const int cl  = tid & 63;
  const int w   = tid >> 6;          // wave 0..7; owns codes w*128..+127
  const int l31 = cl & 31;
  const int l5  = cl >> 5;           // k-group within wave
  const int wg  = blockIdx.x;

  // residual registers: thread owns point rp = tid>>3, dims rj*64 .. +64
  const int rp = tid >> 3;
  const int rj = tid & 7;
  const size_t gp = (size_t)wg * MPTS + rp;
  float4 r4[16];
  {
    const float4* xr = (const float4*)(x + gp * DIM + rj * 64);
    #pragma unroll
    for (int i = 0; i < 16; ++i) r4[i] = xr[i];
  }

  for (int q = 0; q < NUMQ; ++q) {
    // per-lane base into this q's chunk image (chunk stride 32 KB)
    const unsigned char* bq = cbH + ((size_t)q << 20) + (w << 12) + (l5 << 11) + (l31 << 4);

    // issue chunk 0/1 loads BEFORE the A-build so L3 latency hides under it
    BF s0 = loadB(bq);
    BF s1 = loadB(bq + CHUNK_BYTES);

    // ---- A-plane build: f16(resid), swizzled (verbatim R9)
    #pragma unroll
    for (int i = 0; i < 8; ++i) {
      float4 a = r4[2 * i], b = r4[2 * i + 1];
      f16x8 v;
      v[0] = (_Float16)a.x; v[1] = (_Float16)a.y; v[2] = (_Float16)a.z; v[3] = (_Float16)a.w;
      v[4] = (_Float16)b.x; v[5] = (_Float16)b.y; v[6] = (_Float16)b.z; v[7] = (_Float16)b.w;
      int sl = ((i << 3) | rj) ^ (rp & 31);            // swap3(j*8+i) ^ row
      *(f16x8*)(Af + rp * 1024 + (sl << 4)) = v;
    }
    __syncthreads();

    f32x16 acc[2][4];
    #pragma unroll
    for (int mt = 0; mt < 2; ++mt)
      #pragma unroll
      for (int nt = 0; nt < 4; ++nt)
        #pragma unroll
        for (int e = 0; e < 16; ++e) acc[mt][nt][e] = 0.0f;

    // ---- MFMA K-loop: no barriers, no LDS for B; 2-slot register ring
    //      (verbatim R9)
    #pragma unroll 1
    for (int kk = 0; kk < 16; ++kk) {
      const int ks = kk << 1;
      {
        const int s5 = (ks << 1) | l5;
        const int sf = ((((s5 & 7) << 3) | (s5 >> 3)) ^ l31) << 4;
        f16x8 a0 = *(const f16x8*)(Af + l31 * 1024 + sf);
        f16x8 a1 = *(const f16x8*)(Af + 32768 + l31 * 1024 + sf);
        __builtin_amdgcn_s_setprio(1);
        acc[0][0] = __builtin_amdgcn_mfma_f32_32x32x16_f16(a0, s0.b0, acc[0][0], 0, 0, 0);
        acc[0][1] = __builtin_amdgcn_mfma_f32_32x32x16_f16(a0, s0.b1, acc[0][1], 0, 0, 0);
        acc[0][2] = __builtin_amdgcn_mfma_f32_32x32x16_f16(a0, s0.b2, acc[0][2], 0, 0, 0);
        acc[0][3] = __builtin_amdgcn_mfma_f32_32x32x16_f16(a0, s0.b3, acc[0][3], 0, 0, 0);
        acc[1][0] = __builtin_amdgcn_mfma_f32_32x32x16_f16(a1, s0.b0, acc[1][0], 0, 0, 0);
        acc[1][1] = __builtin_amdgcn_mfma_f32_32x32x16_f16(a1, s0.b1, acc[1][1], 0, 0, 0);
        acc[1][2] = __builtin_amdgcn_mfma_f32_32x32x16_f16(a1, s0.b2, acc[1][2], 0, 0, 0);
        acc[1][3] = __builtin_amdgcn_mfma_f32_32x32x16_f16(a1, s0.b3, acc[1][3], 0, 0, 0);
        __builtin_amdgcn_s_setprio(0);
        if (ks + 2 < NCHUNK) s0 = loadB(bq + (size_t)(ks + 2) * CHUNK_BYTES);
      }
      {
        const int ks1 = ks + 1;
        const int s5 = (ks1 << 1) | l5;
        const int sf = ((((s5 & 7) << 3) | (s5 >> 3)) ^ l31) << 4;
        f16x8 a0 = *(const f16x8*)(Af + l31 * 1024 + sf);
        f16x8 a1 = *(const f16x8*)(Af + 32768 + l31 * 1024 + sf);
        __builtin_amdgcn_s_setprio(1);
        acc[0][0] = __builtin_amdgcn_mfma_f32_32x32x16_f16(a0, s1.b0, acc[0][0], 0, 0, 0);
        acc[0][1] = __builtin_amdgcn_mfma_f32_32x32x16_f16(a0, s1.b1, acc[0][1], 0, 0, 0);
        acc[0][2] = __builtin_amdgcn_mfma_f32_32x32x16_f16(a0, s1.b2, acc[0][2], 0, 0, 0);
        acc[0][3] = __builtin_amdgcn_mfma_f32_32x32x16_f16(a0, s1.b3, acc[0][3], 0, 0, 0);
        acc[1][0] = __builtin_amdgcn_mfma_f32_32x32x16_f16(a1, s1.b0, acc[1][0], 0, 0, 0);
        acc[1][1] = __builtin_amdgcn_mfma_f32_32x32x16_f16(a1, s1.b1, acc[1][1], 0, 0, 0);
        acc[1][2] = __builtin_amdgcn_mfma_f32_32x32x16_f16(a1, s1.b2, acc[1][2], 0, 0, 0);
        acc[1][3] = __builtin_amdgcn_mfma_f32_32x32x16_f16(a1, s1.b3, acc[1][3], 0, 0, 0);
        __builtin_amdgcn_s_setprio(0);
        if (ks1 + 2 < NCHUNK) s1 = loadB(bq + (size_t)(ks1 + 2) * CHUNK_BYTES);
      }
    }

    // ---- scores = -2*dot + ||c||^2 (approximate; f16-rounded inputs)
    {
      const float* cnq = cnorm + (q << 10) + (w << 7) + l31;
      const float cn0 = cnq[0], cn1 = cnq[32], cn2 = cnq[64], cn3 = cnq[96];
      #pragma unroll
      for (int mt = 0; mt < 2; ++mt) {
        acc[mt][0] = acc[mt][0] * -2.0f + cn0;
        acc[mt][1] = acc[mt][1] * -2.0f + cn1;
        acc[mt][2] = acc[mt][2] * -2.0f + cn2;
        acc[mt][3] = acc[mt][3] * -2.0f + cn3;
      }
    }

    // ---- FUSED pass 1+3 (R11's proven-correct sweep): per (mt,r) one pass
    //      computes the half-ladder min (== that point's wave-min: each
    //      point's scores live entirely in one 32-lane half), recovers the
    //      id, and ballots candidates vs wave-min margin (superset of the
    //      global-min set since wave-min >= global-min; cap 4/wave).
    // C/D layout 32x32: col = lane&31, row = (r&3)+8*(r>>2)+4*(lane>>5)
    #pragma unroll
    for (int mt = 0; mt < 2; ++mt)
      #pragma unroll
      for (int r = 0; r < 16; ++r) {
        float s = acc[mt][0][r]; int bi = l31;
        if (acc[mt][1][r] < s) { s = acc[mt][1][r]; bi = 32 + l31; }
        if (acc[mt][2][r] < s) { s = acc[mt][2][r]; bi = 64 + l31; }
        if (acc[mt][3][r] < s) { s = acc[mt][3][r]; bi = 96 + l31; }
        float smin = s;
        #pragma unroll
        for (int m = 1; m < 32; m <<= 1) smin = fminf(smin, __shfl_xor(smin, m));
        unsigned long long bm = __ballot(s == smin);
        unsigned halfm = l5 ? (unsigned)(bm >> 32) : (unsigned)bm;
        int first = __builtin_ctz(halfm) + (l5 << 5);
        int id = __shfl(bi, first);
        const float lim = smin + 1.5f + 1e-4f * fabsf(smin);
        unsigned long long b0 = __ballot(acc[mt][0][r] <= lim);
        unsigned long long b1 = __ballot(acc[mt][1][r] <= lim);
        unsigned long long b2 = __ballot(acc[mt][2][r] <= lim);
        unsigned long long b3 = __ballot(acc[mt][3][r] <= lim);
        if (l31 == 0) {
          const int p = mt * 32 + (r & 3) + 8 * (r >> 2) + 4 * l5;
          s1w[p][w] = smin; id1w[p][w] = (unsigned short)id;
          unsigned short* cd = &cand[p][w][0];
          unsigned m0 = (cl == 0) ? (unsigned)b0 : (unsigned)(b0 >> 32);
          unsigned m1 = (cl == 0) ? (unsigned)b1 : (unsigned)(b1 >> 32);
          unsigned m2 = (cl == 0) ? (unsigned)b2 : (unsigned)(b2 >> 32);
          unsigned m3 = (cl == 0) ? (unsigned)b3 : (unsigned)(b3 >> 32);
          int n = 0;
          while (m0 && n < 4) { int bt = __builtin_ctz(m0); m0 &= m0 - 1; cd[n++] = (unsigned short)(bt); }
          while (m1 && n < 4) { int bt = __builtin_ctz(m1); m1 &= m1 - 1; cd[n++] = (unsigned short)(32 + bt); }
          while (m2 && n < 4) { int bt = __builtin_ctz(m2); m2 &= m2 - 1; cd[n++] = (unsigned short)(64 + bt); }
          while (m3 && n < 4) { int bt = __builtin_ctz(m3); m3 &= m3 - 1; cd[n++] = (unsigned short)(96 + bt); }
          ccnt[p][w] = (unsigned char)n;
        }
      }
    __syncthreads();

    // ---- pass 4: group-local global-min (absorbed pass 2) + refinement
    //      tiers, 8-lane-group parallel. Group g of wave w owns p = w*8+g
    //      (== rp for these lanes; exact fp32 residual in-lane).
    {
      const int g  = cl >> 3;
      const int gl = cl & 7;
      const int p  = (w << 3) + g;          // == rp
      // group-local argmin over the 8 per-wave minima (tie: lowest wave,
      // matching R9 pass 2's ascending strict-< scan)
      float bs0 = s1w[p][gl]; int bw = gl; int bid = id1w[p][gl];
      #pragma unroll
      for (int m = 1; m < 8; m <<= 1) {
        float os = __shfl_xor(bs0, m);
        int ow = __shfl_xor(bw, m);
        int oid = __shfl_xor(bid, m);
        if (os < bs0 || (os == bs0 && ow < bw)) { bs0 = os; bw = ow; bid = oid; }
      }
      int winner = bw * 128 + bid;

      int tot = 0;
      #pragma unroll
      for (int ww = 0; ww < 8; ++ww) tot += ccnt[p][ww];
      int mtot = tot;
      #pragma unroll
      for (int m = 1; m < 64; m <<= 1) { int o = __shfl_xor(mtot, m); if (o > mtot) mtot = o; }
      if (mtot > 1) {
        double bs = 1.0e300, bs2 = 1.0e300; int bi = 0x7FFFFFFF;
        #pragma unroll 1
        for (int k = 0; k < mtot; ++k) {
          int cc = -1;
          if (tot > 1 && k < tot) {
            int rem = k, ww = 0;
            #pragma unroll 1
            for (; ww < 7; ++ww) { int nn = ccnt[p][ww]; if (rem < nn) break; rem -= nn; }
            cc = ww * 128 + cand[p][ww][rem];
          }
          double dt = 0.0;
          if (cc >= 0) {
            // tier 1: fp64 dot vs exact fp32 residual (in regs), 4-way ILP
            const float4* cr = (const float4*)(cb + ((size_t)q * CODES + cc) * DIM + gl * 64);
            double d0 = 0, d1 = 0, d2 = 0, d3 = 0;
            #pragma unroll
            for (int i = 0; i < 16; i += 4) {
              float4 c0 = cr[i], c1 = cr[i + 1], c2 = cr[i + 2], c3 = cr[i + 3];
              d0 += (double)r4[i].x * c0.x + (double)r4[i].y * c0.y
                  + (double)r4[i].z * c0.z + (double)r4[i].w * c0.w;
              d1 += (double)r4[i + 1].x * c1.x + (double)r4[i + 1].y * c1.y
                  + (double)r4[i + 1].z * c1.z + (double)r4[i + 1].w * c1.w;
              d2 += (double)r4[i + 2].x * c2.x + (double)r4[i + 2].y * c2.y
                  + (double)r4[i + 2].z * c2.z + (double)r4[i + 2].w * c2.w;
              d3 += (double)r4[i + 3].x * c3.x + (double)r4[i + 3].y * c3.y
                  + (double)r4[i + 3].z * c3.z + (double)r4[i + 3].w * c3.w;
            }
            dt = (d0 + d1) + (d2 + d3);
          }
          #pragma unroll
          for (int m = 1; m < 8; m <<= 1) dt += __shfl_xor(dt, m);
          if (cc >= 0) {
            double s = -2.0 * dt + cnormd[(q << 10) + cc];
            if (s < bs) { bs2 = bs; bs = s; bi = cc; }
            else if (s < bs2) { bs2 = s; }
          }
        }
        // tier 2: exact fp64 chain rebuild from x (rare: <1e-3 gap)
        if (tot > 1 && bs2 - bs <= 1e-3 + 1e-6 * fabs(bs)) {
          bs = 1.0e300; bi = 0x7FFFFFFF;
          const float4* xr2 = (const float4*)(x + gp * DIM + gl * 64);
          #pragma unroll 1
          for (int k = 0; k < tot; ++k) {
            int rem = k, ww = 0;
            #pragma unroll 1
            for (; ww < 7; ++ww) { int nn = ccnt[p][ww]; if (rem < nn) break; rem -= nn; }
            const int cc = ww * 128 + cand[p][ww][rem];
            const float4* cr = (const float4*)(cb + ((size_t)q * CODES + cc) * DIM + gl * 64);
            double dt = 0.0;
            #pragma unroll 1
            for (int i = 0; i < 16; ++i) {
              float4 xv = xr2[i];
              double rhx = xv.x, rhy = xv.y, rhz = xv.z, rhw = xv.w;
              #pragma unroll 1
              for (int t2 = 0; t2 < q; ++t2) {
                const float4* qr = (const float4*)(cb + ((size_t)t2 * CODES + idxs[p][t2]) * DIM + gl * 64);
                float4 qv = qr[i];
                rhx -= (double)qv.x; rhy -= (double)qv.y;
                rhz -= (double)qv.z; rhw -= (double)qv.w;
              }
              float4 cv = cr[i];
              dt += rhx * cv.x + rhy * cv.y + rhz * cv.z + rhw * cv.w;
            }
            #pragma unroll
            for (int m = 1; m < 8; m <<= 1) dt += __shfl_xor(dt, m);
            double s = -2.0 * dt + cnormd[(q << 10) + cc];
            if (s < bs || (s == bs && cc < bi)) { bs = s; bi = cc; }
          }
        }
        if (tot > 1) winner = bi;
      }
      if (gl == 0) idxs[p][q] = (unsigned short)winner;
    }
    __syncthreads();

    // ---- pass 5: residual update (exact fp32 chain) + commit loss (fp64,
    //      2-way ILP partials) — verbatim R9
    {
      const int win = idxs[rp][q];
      const float4* cr = (const float4*)(cb + ((size_t)q * CODES + win) * DIM + rj * 64);
      double ls0 = 0.0, ls1 = 0.0;
      #pragma unroll
      for (int i = 0; i < 16; i += 2) {
        float4 c0 = cr[i], c1 = cr[i + 1];
        float dx0 = c0.x - r4[i].x, dy0 = c0.y - r4[i].y;
        float dz0 = c0.z - r4[i].z, dw0 = c0.w - r4[i].w;
        ls0 += (double)dx0 * dx0 + (double)dy0 * dy0 + (double)dz0 * dz0 + (double)dw0 * dw0;
        r4[i].x -= c0.x; r4[i].y -= c0.y; r4[i].z -= c0.z; r4[i].w -= c0.w;
        float dx1 = c1.x - r4[i + 1].x, dy1 = c1.y - r4[i + 1].y;
        float dz1 = c1.z - r4[i + 1].z, dw1 = c1.w - r4[i + 1].w;
        ls1 += (double)dx1 * dx1 + (double)dy1 * dy1 + (double)dz1 * dz1 + (double)dw1 * dw1;
        r4[i + 1].x -= c1.x; r4[i + 1].y -= c1.y; r4[i + 1].z -= c1.z; r4[i + 1].w -= c1.w;
      }
      double ls = ls0 + ls1;
      #pragma unroll
      for (int m = 1; m < 64; m <<= 1) ls += __shfl_xor(ls, m);
      if (cl == 0) lred[w] = ls;
      __syncthreads();
      if (tid == 0) {
        double t = lred[0] + lred[1] + lred[2] + lred[3]
                 + lred[4] + lred[5] + lred[6] + lred[7];
        atomicAdd(lossAcc + q, t);
      }
      __syncthreads();
    }
  } // q

  // ---- outputs: quantized = x - resid_final; indices as float
  {
    const float4* xr = (const float4*)(x + gp * DIM + rj * 64);
    float4* orow = (float4*)(out + gp * DIM + rj * 64);
    #pragma unroll
    for (int i = 0; i < 16; ++i) {
      float4 xv = xr[i];
      float4 o;
      o.x = xv.x - r4[i].x; o.y = xv.y - r4[i].y;
      o.z = xv.z - r4[i].z; o.w = xv.w - r4[i].w;
      orow[i] = o;
    }
  }
  if (tid < MPTS) {
    float* ob = out + OUT_IDX + ((size_t)wg * MPTS + tid) * NUMQ;
    #pragma unroll
    for (int j = 0; j < NUMQ; ++j) ob[j] = (float)idxs[tid][j];
  }

  // ---- folded k_fin: last block to finish writes the loss outputs.
  // Order-free (any block may be last); device-scope atomics for coherence.
  __threadfence();
  if (tid == 0) {
    unsigned old = atomicAdd(done, 1u);
    if (old == (unsigned)(NWG - 1)) {
      #pragma unroll
      for (int t = 0; t < NUMQ; ++t) {
        double v = atomicAdd(lossAcc + t, 0.0);   // coherent read
        out[OUT_LOSS + t] = (float)(v / (double)((size_t)BATCH * SEQ * DIM));
      }
    }
  }
}

extern "C" void kernel_launch(void* const* d_in, const int* in_sizes, int n_in,
                              void* d_out, int out_size, void* d_ws, size_t ws_size,
                              hipStream_t stream) {
  (void)in_sizes; (void)n_in; (void)out_size; (void)ws_size;
  const float* x  = (const float*)d_in[0];
  const float* cb = (const float*)d_in[1];
  float* out = (float*)d_out;
  char* ws = (char*)d_ws;
  double* loss = (double*)(ws + WS_LOSS);
  float* cnorm = (float*)(ws + WS_CNORM);
  unsigned char* cbH = (unsigned char*)(ws + WS_CBH);   // 8.39 MB
  double* cnormd = (double*)(ws + WS_CNORMD);           // 64 KB
  unsigned* done = (unsigned*)(ws + WS_DONE);

  k_prep<<<NUMQ * NCHUNK * CHUNK_BYTES / 8 / 256, 256, 0, stream>>>(
      cb, cbH, cnorm, cnormd, loss, done);
  k_main<<<NWG, NTHR, 0, stream>>>(x, cb, cbH, cnorm, cnormd, loss, done, out);
}

// Round 10
// 523.974 us; speedup vs baseline: 1.9163x; 1.9138x over previous
//
#include <hip/hip_runtime.h>
#include <cstdint>
#include <cstddef>

// ---------------------------------------------------------------------------
// Residual VQ (SoundStream Alg.1) on MI355X — R13: consolidation.
// R12 post-mortem: R11 (941) and R12 (967) share exactly one element absent
// from R9 (448): the FUSED pass1+3 sweep. Disjoint other changes, identical
// ~950 outcome -> the fused sweep is performance-toxic (acc + ladder + 5
// ballots + divergent extraction in one unrolled region), despite being
// functionally correct. Epilogue reverted to R9 VERBATIM (pass1 / pass2 /
// pass3 / pass4 / pass5 split, two barriers restored).
// Kept from R12: prep-side launch fusion only (k_zero+k_cnorm+k_cnormd+
// k_prep -> one kernel; 6 launches -> 3). k_fin stays separate.
// k_main is byte-for-byte R9 (proven 448 us, absmax 0.03125).
// ---------------------------------------------------------------------------

#define BATCH 8
#define SEQ   2048
#define DIM   512
#define NUMQ  8
#define CODES 1024
#define NPTS  (BATCH*SEQ)            // 16384
#define MPTS  64                     // points per workgroup
#define NWG   (NPTS/MPTS)            // 256 = 1 WG per CU
#define NTHR  512                    // 8 waves
#define NCHUNK 32                    // K-steps of 16 per quantizer
#define CHUNK_BYTES 32768            // per global chunk: [w:8][g:2][c:128][j:8 f16]

#define OUT_IDX   (BATCH*SEQ*DIM)             // 8388608
#define OUT_LOSS  (OUT_IDX + BATCH*SEQ*NUMQ)  // 8519680

#define WS_LOSS   0                           // 8 doubles
#define WS_CNORM  1024                        // 8192 floats
#define WS_CBH    40960                       // f16 chunk images, 8.39 MB
#define WS_CNORMD (WS_CBH + NUMQ*NCHUNK*CHUNK_BYTES)  // 8192 doubles

typedef _Float16 f16x8  __attribute__((ext_vector_type(8)));
typedef _Float16 f16x4  __attribute__((ext_vector_type(4)));
typedef float    f32x16 __attribute__((ext_vector_type(16)));

// ---- fused prep: chunk-image build + fp32/fp64 code norms + loss zeroing --
// grid 4096 x 256. u = global thread = 8B unit of the image (R9's exact map).
__global__ void k_prep(const float* __restrict__ cb, unsigned char* __restrict__ cbH,
                       float* __restrict__ cnorm, double* __restrict__ cnd,
                       double* __restrict__ loss) {
  unsigned u = blockIdx.x * blockDim.x + threadIdx.x;   // 0..1048575
  {
    unsigned h  = u & 1;                 // j-half (4 f16)
    unsigned v  = u >> 1;                // 16B granule
    unsigned c  = v & 127;
    unsigned g  = (v >> 7) & 1;
    unsigned w  = (v >> 8) & 7;
    unsigned ks = (v >> 11) & 31;
    unsigned q  = v >> 16;
    unsigned code = (w << 7) | c;
    unsigned k = ks * 16 + g * 8 + h * 4;
    float4 val = *(const float4*)(cb + ((size_t)((q << 10) | code)) * DIM + k);
    f16x4 o;
    o[0] = (_Float16)val.x; o[1] = (_Float16)val.y;
    o[2] = (_Float16)val.z; o[3] = (_Float16)val.w;
    *(f16x4*)(cbH + (size_t)u * 8) = o;
  }
  if (u < NUMQ) loss[u] = 0.0;
  if (u < NUMQ * CODES) {              // one thread per code row: both norms
    const float4* row = (const float4*)(cb + (size_t)u * DIM);
    float s = 0.f;
    double d0 = 0, d1 = 0, d2 = 0, d3 = 0;
    for (int i = 0; i < 128; i += 4) {
      float4 a = row[i], b = row[i + 1], c2 = row[i + 2], d = row[i + 3];
      s += a.x * a.x + a.y * a.y + a.z * a.z + a.w * a.w
         + b.x * b.x + b.y * b.y + b.z * b.z + b.w * b.w
         + c2.x * c2.x + c2.y * c2.y + c2.z * c2.z + c2.w * c2.w
         + d.x * d.x + d.y * d.y + d.z * d.z + d.w * d.w;
      d0 += (double)a.x * a.x + (double)a.y * a.y + (double)a.z * a.z + (double)a.w * a.w;
      d1 += (double)b.x * b.x + (double)b.y * b.y + (double)b.z * b.z + (double)b.w * b.w;
      d2 += (double)c2.x * c2.x + (double)c2.y * c2.y + (double)c2.z * c2.z + (double)c2.w * c2.w;
      d3 += (double)d.x * d.x + (double)d.y * d.y + (double)d.z * d.z + (double)d.w * d.w;
    }
    cnorm[u] = s;
    cnd[u] = (d0 + d1) + (d2 + d3);
  }
}

// one chunk's 4 B-fragments for this lane (4x global_load_dwordx4, coalesced)
struct BF { f16x8 b0, b1, b2, b3; };
__device__ __forceinline__ BF loadB(const unsigned char* __restrict__ p) {
  BF r;
  r.b0 = *(const f16x8*)(p);
  r.b1 = *(const f16x8*)(p + 512);
  r.b2 = *(const f16x8*)(p + 1024);
  r.b3 = *(const f16x8*)(p + 1536);
  return r;
}

__launch_bounds__(NTHR, 2)
__global__ void k_main(const float* __restrict__ x, const float* __restrict__ cb,
                       const unsigned char* __restrict__ cbH,
                       const float* __restrict__ cnorm,
                       const double* __restrict__ cnormd,
                       double* __restrict__ lossAcc,
                       float* __restrict__ out)
{
  // A-plane: f16 resid, row m (64) x 512 k; 16B slot s=k/8 stored at
  // slot' = swap3(s) ^ (m&31) -> conflict-spread b128 reads and writes.
  __shared__ __align__(16) unsigned char Af[MPTS * DIM * 2];    // 64 KB
  __shared__ float          s1w[MPTS][8];
  __shared__ unsigned short id1w[MPTS][8];
  __shared__ unsigned short cand[MPTS][8][4];
  __shared__ unsigned char  ccnt[MPTS][8];
  __shared__ float          gmA[MPTS];
  __shared__ int            win0A[MPTS];
  __shared__ unsigned short idxs[MPTS][NUMQ];
  __shared__ double         lred[8];

  const int tid = threadIdx.x;
  const int cl  = tid & 63;
  const int w   = tid >> 6;          // wave 0..7; owns codes w*128..+127
  const int l31 = cl & 31;
  const int l5  = cl >> 5;           // k-group within wave
  const int wg  = blockIdx.x;

  // residual registers: thread owns point rp = tid>>3, dims rj*64 .. +64
  const int rp = tid >> 3;
  const int rj = tid & 7;
  const size_t gp = (size_t)wg * MPTS + rp;
  float4 r4[16];
  {
    const float4* xr = (const float4*)(x + gp * DIM + rj * 64);
    #pragma unroll
    for (int i = 0; i < 16; ++i) r4[i] = xr[i];
  }

  for (int q = 0; q < NUMQ; ++q) {
    // per-lane base into this q's chunk image (chunk stride 32 KB)
    const unsigned char* bq = cbH + ((size_t)q << 20) + (w << 12) + (l5 << 11) + (l31 << 4);

    // issue chunk 0/1 loads BEFORE the A-build so L3 latency hides under it
    BF s0 = loadB(bq);
    BF s1 = loadB(bq + CHUNK_BYTES);

    // ---- A-plane build: f16(resid), swizzled (verbatim R6/R8/R9)
    #pragma unroll
    for (int i = 0; i < 8; ++i) {
      float4 a = r4[2 * i], b = r4[2 * i + 1];
      f16x8 v;
      v[0] = (_Float16)a.x; v[1] = (_Float16)a.y; v[2] = (_Float16)a.z; v[3] = (_Float16)a.w;
      v[4] = (_Float16)b.x; v[5] = (_Float16)b.y; v[6] = (_Float16)b.z; v[7] = (_Float16)b.w;
      int sl = ((i << 3) | rj) ^ (rp & 31);            // swap3(j*8+i) ^ row
      *(f16x8*)(Af + rp * 1024 + (sl << 4)) = v;
    }
    __syncthreads();

    f32x16 acc[2][4];
    #pragma unroll
    for (int mt = 0; mt < 2; ++mt)
      #pragma unroll
      for (int nt = 0; nt < 4; ++nt)
        #pragma unroll
        for (int e = 0; e < 16; ++e) acc[mt][nt][e] = 0.0f;

    // ---- MFMA K-loop: no barriers, no LDS for B; 2-slot register ring
    //      (verbatim R9)
    #pragma unroll 1
    for (int kk = 0; kk < 16; ++kk) {
      const int ks = kk << 1;
      {
        const int s5 = (ks << 1) | l5;
        const int sf = ((((s5 & 7) << 3) | (s5 >> 3)) ^ l31) << 4;
        f16x8 a0 = *(const f16x8*)(Af + l31 * 1024 + sf);
        f16x8 a1 = *(const f16x8*)(Af + 32768 + l31 * 1024 + sf);
        __builtin_amdgcn_s_setprio(1);
        acc[0][0] = __builtin_amdgcn_mfma_f32_32x32x16_f16(a0, s0.b0, acc[0][0], 0, 0, 0);
        acc[0][1] = __builtin_amdgcn_mfma_f32_32x32x16_f16(a0, s0.b1, acc[0][1], 0, 0, 0);
        acc[0][2] = __builtin_amdgcn_mfma_f32_32x32x16_f16(a0, s0.b2, acc[0][2], 0, 0, 0);
        acc[0][3] = __builtin_amdgcn_mfma_f32_32x32x16_f16(a0, s0.b3, acc[0][3], 0, 0, 0);
        acc[1][0] = __builtin_amdgcn_mfma_f32_32x32x16_f16(a1, s0.b0, acc[1][0], 0, 0, 0);
        acc[1][1] = __builtin_amdgcn_mfma_f32_32x32x16_f16(a1, s0.b1, acc[1][1], 0, 0, 0);
        acc[1][2] = __builtin_amdgcn_mfma_f32_32x32x16_f16(a1, s0.b2, acc[1][2], 0, 0, 0);
        acc[1][3] = __builtin_amdgcn_mfma_f32_32x32x16_f16(a1, s0.b3, acc[1][3], 0, 0, 0);
        __builtin_amdgcn_s_setprio(0);
        if (ks + 2 < NCHUNK) s0 = loadB(bq + (size_t)(ks + 2) * CHUNK_BYTES);
      }
      {
        const int ks1 = ks + 1;
        const int s5 = (ks1 << 1) | l5;
        const int sf = ((((s5 & 7) << 3) | (s5 >> 3)) ^ l31) << 4;
        f16x8 a0 = *(const f16x8*)(Af + l31 * 1024 + sf);
        f16x8 a1 = *(const f16x8*)(Af + 32768 + l31 * 1024 + sf);
        __builtin_amdgcn_s_setprio(1);
        acc[0][0] = __builtin_amdgcn_mfma_f32_32x32x16_f16(a0, s1.b0, acc[0][0], 0, 0, 0);
        acc[0][1] = __builtin_amdgcn_mfma_f32_32x32x16_f16(a0, s1.b1, acc[0][1], 0, 0, 0);
        acc[0][2] = __builtin_amdgcn_mfma_f32_32x32x16_f16(a0, s1.b2, acc[0][2], 0, 0, 0);
        acc[0][3] = __builtin_amdgcn_mfma_f32_32x32x16_f16(a0, s1.b3, acc[0][3], 0, 0, 0);
        acc[1][0] = __builtin_amdgcn_mfma_f32_32x32x16_f16(a1, s1.b0, acc[1][0], 0, 0, 0);
        acc[1][1] = __builtin_amdgcn_mfma_f32_32x32x16_f16(a1, s1.b1, acc[1][1], 0, 0, 0);
        acc[1][2] = __builtin_amdgcn_mfma_f32_32x32x16_f16(a1, s1.b2, acc[1][2], 0, 0, 0);
        acc[1][3] = __builtin_amdgcn_mfma_f32_32x32x16_f16(a1, s1.b3, acc[1][3], 0, 0, 0);
        __builtin_amdgcn_s_setprio(0);
        if (ks1 + 2 < NCHUNK) s1 = loadB(bq + (size_t)(ks1 + 2) * CHUNK_BYTES);
      }
    }

    // ---- scores = -2*dot + ||c||^2 (approximate; f16-rounded inputs)
    {
      const float* cnq = cnorm + (q << 10) + (w << 7) + l31;
      const float cn0 = cnq[0], cn1 = cnq[32], cn2 = cnq[64], cn3 = cnq[96];
      #pragma unroll
      for (int mt = 0; mt < 2; ++mt) {
        acc[mt][0] = acc[mt][0] * -2.0f + cn0;
        acc[mt][1] = acc[mt][1] * -2.0f + cn1;
        acc[mt][2] = acc[mt][2] * -2.0f + cn2;
        acc[mt][3] = acc[mt][3] * -2.0f + cn3;
      }
    }

    // ---- pass 1: per-wave per-point top-1, score-only ladder + ballot id.
    // C/D layout 32x32: col = lane&31, row = (r&3)+8*(r>>2)+4*(lane>>5)
    #pragma unroll
    for (int mt = 0; mt < 2; ++mt)
      #pragma unroll
      for (int r = 0; r < 16; ++r) {
        float s = acc[mt][0][r]; int bi = l31;
        if (acc[mt][1][r] < s) { s = acc[mt][1][r]; bi = 32 + l31; }
        if (acc[mt][2][r] < s) { s = acc[mt][2][r]; bi = 64 + l31; }
        if (acc[mt][3][r] < s) { s = acc[mt][3][r]; bi = 96 + l31; }
        float smin = s;
        #pragma unroll
        for (int m = 1; m < 32; m <<= 1) smin = fminf(smin, __shfl_xor(smin, m));
        unsigned long long bm = __ballot(s == smin);
        unsigned half = l5 ? (unsigned)(bm >> 32) : (unsigned)bm;
        int first = __builtin_ctz(half) + (l5 << 5);
        int id = __shfl(bi, first);
        if (l31 == 0) {
          int p = mt * 32 + (r & 3) + 8 * (r >> 2) + 4 * l5;
          s1w[p][w] = smin; id1w[p][w] = (unsigned short)id;
        }
      }
    __syncthreads();

    // ---- pass 2: global min + provisional winner per point
    if (tid < MPTS) {
      int p = tid;
      float bs = s1w[p][0]; int bi = id1w[p][0];
      #pragma unroll
      for (int ww = 1; ww < 8; ++ww) {
        float s = s1w[p][ww];
        if (s < bs) { bs = s; bi = ww * 128 + id1w[p][ww]; }
      }
      gmA[p] = bs; win0A[p] = bi;
    }
    __syncthreads();

    // ---- pass 3: ballot candidates within margin of global min
    //      (margin 1.5 vs f16 score error sigma~0.03; proven R4-R9)
    #pragma unroll
    for (int mt = 0; mt < 2; ++mt)
      #pragma unroll
      for (int r = 0; r < 16; ++r) {
        const int p0 = mt * 32 + (r & 3) + 8 * (r >> 2);
        const float g0 = gmA[p0], g1 = gmA[p0 + 4];
        const float lim0 = g0 + 1.5f + 1e-4f * fabsf(g0);
        const float lim1 = g1 + 1.5f + 1e-4f * fabsf(g1);
        const float lim = l5 ? lim1 : lim0;
        unsigned long long b0 = __ballot(acc[mt][0][r] <= lim);
        unsigned long long b1 = __ballot(acc[mt][1][r] <= lim);
        unsigned long long b2 = __ballot(acc[mt][2][r] <= lim);
        unsigned long long b3 = __ballot(acc[mt][3][r] <= lim);
        if (cl == 0 || cl == 32) {
          const int p = p0 + (cl >> 3);
          unsigned short* cd = &cand[p][w][0];
          unsigned m0 = (cl == 0) ? (unsigned)b0 : (unsigned)(b0 >> 32);
          unsigned m1 = (cl == 0) ? (unsigned)b1 : (unsigned)(b1 >> 32);
          unsigned m2 = (cl == 0) ? (unsigned)b2 : (unsigned)(b2 >> 32);
          unsigned m3 = (cl == 0) ? (unsigned)b3 : (unsigned)(b3 >> 32);
          int n = 0;
          while (m0 && n < 4) { int bt = __builtin_ctz(m0); m0 &= m0 - 1; cd[n++] = (unsigned short)(bt); }
          while (m1 && n < 4) { int bt = __builtin_ctz(m1); m1 &= m1 - 1; cd[n++] = (unsigned short)(32 + bt); }
          while (m2 && n < 4) { int bt = __builtin_ctz(m2); m2 &= m2 - 1; cd[n++] = (unsigned short)(64 + bt); }
          while (m3 && n < 4) { int bt = __builtin_ctz(m3); m3 &= m3 - 1; cd[n++] = (unsigned short)(96 + bt); }
          ccnt[p][w] = (unsigned char)n;
        }
      }
    __syncthreads();

    // ---- pass 4: refinement tiers, 8-lane-group parallel (verbatim R9).
    //      Group g = cl>>3 of wave w refines point p = w*8+g (== rp).
    {
      const int g  = cl >> 3;
      const int gl = cl & 7;
      const int p  = (w << 3) + g;          // == rp
      int tot = 0;
      #pragma unroll
      for (int ww = 0; ww < 8; ++ww) tot += ccnt[p][ww];
      int winner = win0A[p];
      int mtot = tot;
      #pragma unroll
      for (int m = 1; m < 64; m <<= 1) { int o = __shfl_xor(mtot, m); if (o > mtot) mtot = o; }
      if (mtot > 1) {
        double bs = 1.0e300, bs2 = 1.0e300; int bi = 0x7FFFFFFF;
        #pragma unroll 1
        for (int k = 0; k < mtot; ++k) {
          int cc = -1;
          if (tot > 1 && k < tot) {
            int rem = k, ww = 0;
            #pragma unroll 1
            for (; ww < 7; ++ww) { int nn = ccnt[p][ww]; if (rem < nn) break; rem -= nn; }
            cc = ww * 128 + cand[p][ww][rem];
          }
          double dt = 0.0;
          if (cc >= 0) {
            // tier 1: fp64 dot vs exact fp32 residual (in regs), 4-way ILP
            const float4* cr = (const float4*)(cb + ((size_t)q * CODES + cc) * DIM + gl * 64);
            double d0 = 0, d1 = 0, d2 = 0, d3 = 0;
            #pragma unroll
            for (int i = 0; i < 16; i += 4) {
              float4 c0 = cr[i], c1 = cr[i + 1], c2 = cr[i + 2], c3 = cr[i + 3];
              d0 += (double)r4[i].x * c0.x + (double)r4[i].y * c0.y
                  + (double)r4[i].z * c0.z + (double)r4[i].w * c0.w;
              d1 += (double)r4[i + 1].x * c1.x + (double)r4[i + 1].y * c1.y
                  + (double)r4[i + 1].z * c1.z + (double)r4[i + 1].w * c1.w;
              d2 += (double)r4[i + 2].x * c2.x + (double)r4[i + 2].y * c2.y
                  + (double)r4[i + 2].z * c2.z + (double)r4[i + 2].w * c2.w;
              d3 += (double)r4[i + 3].x * c3.x + (double)r4[i + 3].y * c3.y
                  + (double)r4[i + 3].z * c3.z + (double)r4[i + 3].w * c3.w;
            }
            dt = (d0 + d1) + (d2 + d3);
          }
          #pragma unroll
          for (int m = 1; m < 8; m <<= 1) dt += __shfl_xor(dt, m);
          if (cc >= 0) {
            double s = -2.0 * dt + cnormd[(q << 10) + cc];
            if (s < bs) { bs2 = bs; bs = s; bi = cc; }
            else if (s < bs2) { bs2 = s; }
          }
        }
        // tier 2: exact fp64 chain rebuild from x (rare: <1e-3 gap)
        if (tot > 1 && bs2 - bs <= 1e-3 + 1e-6 * fabs(bs)) {
          bs = 1.0e300; bi = 0x7FFFFFFF;
          const float4* xr2 = (const float4*)(x + gp * DIM + gl * 64);
          #pragma unroll 1
          for (int k = 0; k < tot; ++k) {
            int rem = k, ww = 0;
            #pragma unroll 1
            for (; ww < 7; ++ww) { int nn = ccnt[p][ww]; if (rem < nn) break; rem -= nn; }
            const int cc = ww * 128 + cand[p][ww][rem];
            const float4* cr = (const float4*)(cb + ((size_t)q * CODES + cc) * DIM + gl * 64);
            double dt = 0.0;
            #pragma unroll 1
            for (int i = 0; i < 16; ++i) {
              float4 xv = xr2[i];
              double rhx = xv.x, rhy = xv.y, rhz = xv.z, rhw = xv.w;
              #pragma unroll 1
              for (int t2 = 0; t2 < q; ++t2) {
                const float4* qr = (const float4*)(cb + ((size_t)t2 * CODES + idxs[p][t2]) * DIM + gl * 64);
                float4 qv = qr[i];
                rhx -= (double)qv.x; rhy -= (double)qv.y;
                rhz -= (double)qv.z; rhw -= (double)qv.w;
              }
              float4 cv = cr[i];
              dt += rhx * cv.x + rhy * cv.y + rhz * cv.z + rhw * cv.w;
            }
            #pragma unroll
            for (int m = 1; m < 8; m <<= 1) dt += __shfl_xor(dt, m);
            double s = -2.0 * dt + cnormd[(q << 10) + cc];
            if (s < bs || (s == bs && cc < bi)) { bs = s; bi = cc; }
          }
        }
        if (tot > 1) winner = bi;
      }
      if (gl == 0) idxs[p][q] = (unsigned short)winner;
    }
    __syncthreads();

    // ---- pass 5: residual update (exact fp32 chain) + commit loss (fp64,
    //      2-way ILP partials) — verbatim R9
    {
      const int win = idxs[rp][q];
      const float4* cr = (const float4*)(cb + ((size_t)q * CODES + win) * DIM + rj * 64);
      double ls0 = 0.0, ls1 = 0.0;
      #pragma unroll
      for (int i = 0; i < 16; i += 2) {
        float4 c0 = cr[i], c1 = cr[i + 1];
        float dx0 = c0.x - r4[i].x, dy0 = c0.y - r4[i].y;
        float dz0 = c0.z - r4[i].z, dw0 = c0.w - r4[i].w;
        ls0 += (double)dx0 * dx0 + (double)dy0 * dy0 + (double)dz0 * dz0 + (double)dw0 * dw0;
        r4[i].x -= c0.x; r4[i].y -= c0.y; r4[i].z -= c0.z; r4[i].w -= c0.w;
        float dx1 = c1.x - r4[i + 1].x, dy1 = c1.y - r4[i + 1].y;
        float dz1 = c1.z - r4[i + 1].z, dw1 = c1.w - r4[i + 1].w;
        ls1 += (double)dx1 * dx1 + (double)dy1 * dy1 + (double)dz1 * dz1 + (double)dw1 * dw1;
        r4[i + 1].x -= c1.x; r4[i + 1].y -= c1.y; r4[i + 1].z -= c1.z; r4[i + 1].w -= c1.w;
      }
      double ls = ls0 + ls1;
      #pragma unroll
      for (int m = 1; m < 64; m <<= 1) ls += __shfl_xor(ls, m);
      if (cl == 0) lred[w] = ls;
      __syncthreads();
      if (tid == 0) {
        double t = lred[0] + lred[1] + lred[2] + lred[3]
                 + lred[4] + lred[5] + lred[6] + lred[7];
        atomicAdd(lossAcc + q, t);
      }
      __syncthreads();
    }
  } // q

  // ---- outputs: quantized = x - resid_final; indices as float
  {
    const float4* xr = (const float4*)(x + gp * DIM + rj * 64);
    float4* orow = (float4*)(out + gp * DIM + rj * 64);
    #pragma unroll
    for (int i = 0; i < 16; ++i) {
      float4 xv = xr[i];
      float4 o;
      o.x = xv.x - r4[i].x; o.y = xv.y - r4[i].y;
      o.z = xv.z - r4[i].z; o.w = xv.w - r4[i].w;
      orow[i] = o;
    }
  }
  if (tid < MPTS) {
    float* ob = out + OUT_IDX + ((size_t)wg * MPTS + tid) * NUMQ;
    #pragma unroll
    for (int j = 0; j < NUMQ; ++j) ob[j] = (float)idxs[tid][j];
  }
}

__global__ void k_fin(const double* __restrict__ loss, float* __restrict__ out) {
  int t = threadIdx.x;
  if (t < NUMQ)
    out[OUT_LOSS + t] = (float)(loss[t] / (double)((size_t)BATCH * SEQ * DIM));
}

extern "C" void kernel_launch(void* const* d_in, const int* in_sizes, int n_in,
                              void* d_out, int out_size, void* d_ws, size_t ws_size,
                              hipStream_t stream) {
  (void)in_sizes; (void)n_in; (void)out_size; (void)ws_size;
  const float* x  = (const float*)d_in[0];
  const float* cb = (const float*)d_in[1];
  float* out = (float*)d_out;
  char* ws = (char*)d_ws;
  double* loss = (double*)(ws + WS_LOSS);
  float* cnorm = (float*)(ws + WS_CNORM);
  unsigned char* cbH = (unsigned char*)(ws + WS_CBH);   // 8.39 MB
  double* cnormd = (double*)(ws + WS_CNORMD);           // 64 KB

  k_prep<<<NUMQ * NCHUNK * CHUNK_BYTES / 8 / 256, 256, 0, stream>>>(
      cb, cbH, cnorm, cnormd, loss);
  k_main<<<NWG, NTHR, 0, stream>>>(x, cb, cbH, cnorm, cnormd, loss, out);
  k_fin<<<1, 64, 0, stream>>>(loss, out);
}